// Round 4
// baseline (74.261 us; speedup 1.0000x reference)
//
#include <hip/hip_runtime.h>
#include <math.h>

// Problem constants (match reference)
constexpr int   T_DIM = 4096;
constexpr int   NC    = 10;
constexpr int   CHUNK = 1024;            // columns per block
constexpr int   NCH   = T_DIM / CHUNK;   // 4 chunks per row
constexpr int   NTHR  = 256;             // 4 waves
constexpr int   NWAVE = 4;

constexpr float EPS_C   = 0.2f;
constexpr float ALPHA_C = 0.5f;
constexpr float GAMMA_C = 1e-4f;
constexpr float MU_C    = 8e-4f;

// ws layout (floats): Smean[B*T] | Amean[B*T] | cmax[B*NCH] | cmin[B*NCH]

__global__ __launch_bounds__(NTHR) void mbs_k1(
    const float* __restrict__ scores,
    const float* __restrict__ attw,
    const int*   __restrict__ seqlen,
    float*       __restrict__ ws,
    float*       __restrict__ out,
    int B)
{
    float* Smean = ws;
    float* Amean = ws + (size_t)B * T_DIM;
    float* cmax  = Amean + (size_t)B * T_DIM;
    float* cmin  = cmax + (size_t)B * NCH;

    __shared__ float slabS[NWAVE][CHUNK];   // 16 KB
    __shared__ float slabA[NWAVE][CHUNK];   // 16 KB
    __shared__ float red[NWAVE][7];

    const int bid  = blockIdx.x;
    const int row  = bid >> 2;
    const int q    = bid & 3;
    const int tid  = threadIdx.x;
    const int lane = tid & 63;
    const int w    = tid >> 6;
    const int slen = seqlen[row];
    const int c0   = q * CHUNK;            // global col of chunk start

    if (c0 >= slen) {                      // fully-masked chunk: sentinels only
        if (tid == 0) {
            cmax[row * NCH + q] = -INFINITY;
            cmin[row * NCH + q] =  INFINITY;
        }
        return;
    }

    // ---- per-wave CONTIGUOUS channel-row sweeps (DRAM page-friendly) ----
    // 20 channel-segments (10 scores + 10 attw) of 4 KB each; wave w owns
    // segments {w, w+4, w+8, w+12, w+16}. Each segment = 4 contiguous 1 KB
    // wave-loads. Channels combine across waves via LDS slabs.
    float4 ps[4], pa[4];
#pragma unroll
    for (int k = 0; k < 4; ++k) {
        ps[k] = make_float4(0.f, 0.f, 0.f, 0.f);
        pa[k] = make_float4(0.f, 0.f, 0.f, 0.f);
    }
    const size_t rowoff = (size_t)row * NC * T_DIM + c0;
#pragma unroll
    for (int j = 0; j < 5; ++j) {
        const int  s   = w + 4 * j;        // 0..19, wave-uniform
        const bool isS = s < 10;
        const int  c   = isS ? s : s - 10;
        const float* base = (isS ? scores : attw) + rowoff + (size_t)c * T_DIM;
#pragma unroll
        for (int k = 0; k < 4; ++k) {
            if (c0 + k * 256 < slen) {     // skip fully-masked 1KB slices
                const float4 v = *reinterpret_cast<const float4*>(base + k * 256 + lane * 4);
                if (isS) { ps[k].x += v.x; ps[k].y += v.y; ps[k].z += v.z; ps[k].w += v.w; }
                else     { pa[k].x += v.x; pa[k].y += v.y; pa[k].z += v.z; pa[k].w += v.w; }
            }
        }
    }
#pragma unroll
    for (int k = 0; k < 4; ++k) {
        *reinterpret_cast<float4*>(&slabS[w][k * 256 + lane * 4]) = ps[k];
        *reinterpret_cast<float4*>(&slabA[w][k * 256 + lane * 4]) = pa[k];
    }
    __syncthreads();

    // ---- combine waves -> channel means; write to ws ----
    const int  g0     = c0 + tid * 4;
    const bool active = g0 < slen;
    float4 s4 = make_float4(0.f, 0.f, 0.f, 0.f);
    float4 a4 = make_float4(0.f, 0.f, 0.f, 0.f);
    if (active) {
#pragma unroll
        for (int w2 = 0; w2 < NWAVE; ++w2) {
            const float4 sv = *reinterpret_cast<const float4*>(&slabS[w2][tid * 4]);
            const float4 av = *reinterpret_cast<const float4*>(&slabA[w2][tid * 4]);
            s4.x += sv.x; s4.y += sv.y; s4.z += sv.z; s4.w += sv.w;
            a4.x += av.x; a4.y += av.y; a4.z += av.z; a4.w += av.w;
        }
        const float invNC = 1.0f / (float)NC;
        s4.x *= invNC; s4.y *= invNC; s4.z *= invNC; s4.w *= invNC;
        a4.x *= invNC; a4.y *= invNC; a4.z *= invNC; a4.w *= invNC;
        *reinterpret_cast<float4*>(Smean + (size_t)row * T_DIM + g0) = s4;
        *reinterpret_cast<float4*>(Amean + (size_t)row * T_DIM + g0) = a4;
    }

    // ---- theta-independent partials + masked max/min ----
    const bool pos  = row < (B >> 1);
    const bool isLG = (row == (B >> 1) - 1) || (row == B - 1);
    const float sarr[4] = {s4.x, s4.y, s4.z, s4.w};
    const float aarr[4] = {a4.x, a4.y, a4.z, a4.w};
    float mx = -INFINITY, mn = INFINITY;
    float v0 = 0.f, v1 = 0.f, v4 = 0.f, v5 = 0.f, v7 = 0.f;
    if (active) {
#pragma unroll
        for (int j = 0; j < 4; ++j) {
            if (g0 + j < slen) {
                const float s  = sarr[j];
                const float a  = aarr[j];
                const float sa = s * a;
                mx = fmaxf(mx, a);
                mn = fminf(mn, a);
                if (pos) {
                    v0 += fmaxf(__logf(s),  -100.0f);
                    v1 += fmaxf(__logf(sa), -100.0f);
                    v4 += fabsf(a);
                    if (isLG) v5 += (a - s) * (a - s);
                } else {
                    v0 += fmaxf(__logf(1.0f - s),  -100.0f);
                    v1 += fmaxf(__logf(1.0f - sa), -100.0f);
                    if (isLG) v5 += a * a;
                }
                v7 += s + sa;
            }
        }
    }

    float vals[7] = {mx, mn, v0, v1, v4, v5, v7};
#pragma unroll
    for (int off = 32; off; off >>= 1) {
        vals[0] = fmaxf(vals[0], __shfl_down(vals[0], off, 64));
        vals[1] = fminf(vals[1], __shfl_down(vals[1], off, 64));
#pragma unroll
        for (int k = 2; k < 7; ++k)
            vals[k] += __shfl_down(vals[k], off, 64);
    }
    if (lane == 0)
#pragma unroll
        for (int k = 0; k < 7; ++k) red[w][k] = vals[k];
    __syncthreads();

    if (tid == 0) {
        float tmx = red[0][0], tmn = red[0][1];
        float t0 = red[0][2], t1 = red[0][3], t4 = red[0][4],
              t5 = red[0][5], t7 = red[0][6];
#pragma unroll
        for (int w2 = 1; w2 < NWAVE; ++w2) {
            tmx = fmaxf(tmx, red[w2][0]);
            tmn = fminf(tmn, red[w2][1]);
            t0 += red[w2][2]; t1 += red[w2][3]; t4 += red[w2][4];
            t5 += red[w2][5]; t7 += red[w2][6];
        }
        cmax[row * NCH + q] = tmx;
        cmin[row * NCH + q] = tmn;

        const float inv_slen = 1.0f / (float)slen;
        const float invB2    = 2.0f / (float)B;   // 1/128
        atomicAdd(out + 0, ALPHA_C * (-t0 * inv_slen) * invB2);
        atomicAdd(out + 1, ALPHA_C * (-t1 * inv_slen) * invB2);
        if (pos)               atomicAdd(out + 4, GAMMA_C * t4 * invB2);
        if (row == B - 1)        atomicAdd(out + 5, t5 * inv_slen);  // LG_0
        if (row == (B >> 1) - 1) atomicAdd(out + 6, t5 * inv_slen);  // LG_1
        atomicAdd(out + 8, t7 * invB2);
    }
}

__global__ __launch_bounds__(NTHR) void mbs_k2(
    const int* __restrict__ seqlen,
    const float* __restrict__ ws,
    float*     __restrict__ out,
    int B)
{
    const float* Smean = ws;
    const float* Amean = ws + (size_t)B * T_DIM;
    const float* cmax  = Amean + (size_t)B * T_DIM;
    const float* cmin  = cmax + (size_t)B * NCH;

    __shared__ float red[NWAVE][3];

    const int bid  = blockIdx.x;
    const int row  = bid >> 2;
    const int q    = bid & 3;
    const int tid  = threadIdx.x;
    const int lane = tid & 63;
    const int w    = tid >> 6;
    const int slen = seqlen[row];
    const int g0   = q * CHUNK + tid * 4;

    if (q * CHUNK >= slen) return;   // block-uniform, before any barrier

    // per-row theta from chunk partials
    float mx = -INFINITY, mn = INFINITY;
#pragma unroll
    for (int c = 0; c < NCH; ++c) {
        mx = fmaxf(mx, cmax[row * NCH + c]);
        mn = fminf(mn, cmin[row * NCH + c]);
    }
    const float theta = (mx - mn) * EPS_C + mn;
    const bool pos    = row < (B >> 1);
    const bool active = g0 < slen;

    float v2 = 0.f, v3 = 0.f, v6 = 0.f;
    if (active) {
        const float4 s4 = *reinterpret_cast<const float4*>(Smean + (size_t)row * T_DIM + g0);
        const float4 a4 = *reinterpret_cast<const float4*>(Amean + (size_t)row * T_DIM + g0);
        const float sarr[4] = {s4.x, s4.y, s4.z, s4.w};
        const float aarr[4] = {a4.x, a4.y, a4.z, a4.w};
#pragma unroll
        for (int j = 0; j < 4; ++j) {
            const int t = g0 + j;
            const float s  = sarr[j];
            const float a  = aarr[j];
            const float sa = s * a;
            if (t < slen) {
                const bool sup = a < theta;
                if (pos) {
                    v2 += sup ? fmaxf(__logf(s),  -100.0f) : -100.0f;
                    v3 += sup ? fmaxf(__logf(sa), -100.0f) : -100.0f;
                } else if (sup) {
                    v2 += fmaxf(__logf(1.0f - s),  -100.0f);
                    v3 += fmaxf(__logf(1.0f - sa), -100.0f);
                }
            }
            if (t < slen - 1) {
                float s2, a2;
                if (j < 3) { s2 = sarr[j + 1]; a2 = aarr[j + 1]; }
                else {
                    s2 = Smean[(size_t)row * T_DIM + t + 1];
                    a2 = Amean[(size_t)row * T_DIM + t + 1];
                }
                const float ds  = s  - s2;
                const float dsa = sa - s2 * a2;
                v6 += ds * ds + dsa * dsa;
            }
        }
    }

    float vals[3] = {v2, v3, v6};
#pragma unroll
    for (int off = 32; off; off >>= 1)
#pragma unroll
        for (int k = 0; k < 3; ++k)
            vals[k] += __shfl_down(vals[k], off, 64);
    if (lane == 0)
#pragma unroll
        for (int k = 0; k < 3; ++k) red[w][k] = vals[k];
    __syncthreads();

    if (tid == 0) {
        float t2 = red[0][0], t3 = red[0][1], t6 = red[0][2];
#pragma unroll
        for (int w2 = 1; w2 < NWAVE; ++w2) {
            t2 += red[w2][0]; t3 += red[w2][1]; t6 += red[w2][2];
        }
        const float inv_slen = 1.0f / (float)slen;
        const float invB2    = 2.0f / (float)B;
        atomicAdd(out + 2, (1.0f - ALPHA_C) * (-t2 * inv_slen) * invB2);
        atomicAdd(out + 3, (1.0f - ALPHA_C) * (-t3 * inv_slen) * invB2);
        atomicAdd(out + 7, MU_C * t6 * invB2);
    }
}

extern "C" void kernel_launch(void* const* d_in, const int* in_sizes, int n_in,
                              void* d_out, int out_size, void* d_ws, size_t ws_size,
                              hipStream_t stream) {
    const float* scores = (const float*)d_in[0];
    const float* attw   = (const float*)d_in[1];
    // d_in[2] = label (unused: reference splits by fixed B/2)
    const int*   seqlen = (const int*)d_in[3];
    const int B = in_sizes[2];
    const int grid = B * NCH;

    hipMemsetAsync(d_out, 0, out_size * sizeof(float), stream);
    mbs_k1<<<dim3(grid), dim3(NTHR), 0, stream>>>(scores, attw, seqlen,
                                                  (float*)d_ws, (float*)d_out, B);
    mbs_k2<<<dim3(grid), dim3(NTHR), 0, stream>>>(seqlen, (const float*)d_ws,
                                                  (float*)d_out, B);
}

// Round 5
// 47.240 us; speedup vs baseline: 1.5720x; 1.5720x over previous
//
#include <hip/hip_runtime.h>
#include <math.h>

// Problem constants (match reference)
constexpr int   T_DIM = 4096;
constexpr int   NC    = 10;
constexpr int   CHUNK = 1024;            // columns per A-block
constexpr int   NCH   = T_DIM / CHUNK;   // 4 chunks per row
constexpr int   ATHR  = 256;             // A: 4 waves, no LDS pressure
constexpr int   BTHR  = 1024;            // B: 16 waves, one block per row
constexpr int   BWAVE = BTHR / 64;

constexpr float EPS_C   = 0.2f;
constexpr float ALPHA_C = 0.5f;
constexpr float GAMMA_C = 1e-4f;
constexpr float MU_C    = 8e-4f;

// ws layout (floats): Smean[B*T] | Amean[B*T] | cmax[B*NCH] | cmin[B*NCH]

// ---------------------------------------------------------------------------
// Kernel A: pure streaming. Straight-line 20-load body (max MLP), balanced
// (row,chunk) grid. Writes channel means + per-chunk masked max/min of A.
// ---------------------------------------------------------------------------
__global__ __launch_bounds__(ATHR) void mbs_means(
    const float* __restrict__ scores,
    const float* __restrict__ attw,
    const int*   __restrict__ seqlen,
    float*       __restrict__ ws,
    int B)
{
    float* Smean = ws;
    float* Amean = ws + (size_t)B * T_DIM;
    float* cmax  = Amean + (size_t)B * T_DIM;
    float* cmin  = cmax + (size_t)B * NCH;

    const int bid  = blockIdx.x;
    const int row  = bid >> 2;
    const int q    = bid & 3;
    const int tid  = threadIdx.x;
    const int lane = tid & 63;
    const int w    = tid >> 6;
    const int slen = seqlen[row];
    const int g0   = q * CHUNK + tid * 4;

    if (q * CHUNK >= slen) {               // fully-masked chunk: sentinels only
        if (tid == 0) {
            cmax[row * NCH + q] = -INFINITY;
            cmin[row * NCH + q] =  INFINITY;
        }
        return;
    }
    const bool active = g0 < slen;

    float4 s4 = make_float4(0.f, 0.f, 0.f, 0.f);
    float4 a4 = make_float4(0.f, 0.f, 0.f, 0.f);
    if (active) {
        const float* sp = scores + (size_t)row * NC * T_DIM + g0;
        const float* ap = attw   + (size_t)row * NC * T_DIM + g0;
#pragma unroll
        for (int c = 0; c < NC; ++c) {     // 20 unconditional loads, no branches
            const float4 sv = *reinterpret_cast<const float4*>(sp + (size_t)c * T_DIM);
            const float4 av = *reinterpret_cast<const float4*>(ap + (size_t)c * T_DIM);
            s4.x += sv.x; s4.y += sv.y; s4.z += sv.z; s4.w += sv.w;
            a4.x += av.x; a4.y += av.y; a4.z += av.z; a4.w += av.w;
        }
        const float invNC = 1.0f / (float)NC;
        s4.x *= invNC; s4.y *= invNC; s4.z *= invNC; s4.w *= invNC;
        a4.x *= invNC; a4.y *= invNC; a4.z *= invNC; a4.w *= invNC;
        *reinterpret_cast<float4*>(Smean + (size_t)row * T_DIM + g0) = s4;
        *reinterpret_cast<float4*>(Amean + (size_t)row * T_DIM + g0) = a4;
    }

    // masked max/min of A-mean for theta
    float mx = -INFINITY, mn = INFINITY;
    if (active) {
        const float aarr[4] = {a4.x, a4.y, a4.z, a4.w};
#pragma unroll
        for (int j = 0; j < 4; ++j) {
            if (g0 + j < slen) {
                mx = fmaxf(mx, aarr[j]);
                mn = fminf(mn, aarr[j]);
            }
        }
    }
#pragma unroll
    for (int off = 32; off; off >>= 1) {
        mx = fmaxf(mx, __shfl_down(mx, off, 64));
        mn = fminf(mn, __shfl_down(mn, off, 64));
    }
    __shared__ float rmx[ATHR / 64], rmn[ATHR / 64];
    if (lane == 0) { rmx[w] = mx; rmn[w] = mn; }
    __syncthreads();
    if (tid == 0) {
        float tmx = rmx[0], tmn = rmn[0];
#pragma unroll
        for (int w2 = 1; w2 < ATHR / 64; ++w2) {
            tmx = fmaxf(tmx, rmx[w2]);
            tmn = fminf(tmn, rmn[w2]);
        }
        cmax[row * NCH + q] = tmx;
        cmin[row * NCH + q] = tmn;
    }
}

// ---------------------------------------------------------------------------
// Kernel B: one block per row. Reads only the (L2/L3-hot) means; computes
// theta and ALL nine reductions; plain device atomics to d_out.
// ---------------------------------------------------------------------------
__global__ __launch_bounds__(BTHR) void mbs_final(
    const int*   __restrict__ seqlen,
    const float* __restrict__ ws,
    float*       __restrict__ out,
    int B)
{
    const float* Smean = ws;
    const float* Amean = ws + (size_t)B * T_DIM;
    const float* cmax  = Amean + (size_t)B * T_DIM;
    const float* cmin  = cmax + (size_t)B * NCH;

    const int row  = blockIdx.x;
    const int tid  = threadIdx.x;
    const int lane = tid & 63;
    const int w    = tid >> 6;
    const int slen = seqlen[row];
    const bool pos  = row < (B >> 1);
    const bool isLG = (row == (B >> 1) - 1) || (row == B - 1);
    const int t0   = tid * 4;
    const bool active = t0 < slen;

    float mx = -INFINITY, mn = INFINITY;
#pragma unroll
    for (int c = 0; c < NCH; ++c) {
        mx = fmaxf(mx, cmax[row * NCH + c]);
        mn = fminf(mn, cmin[row * NCH + c]);
    }
    const float theta = (mx - mn) * EPS_C + mn;

    // v0=bce(S) v1=bce(SA) v2=sup-bce(S) v3=sup-bce(SA)
    // v4=sum|A| v5=LG sum v6=smooth v7=spread
    float v0 = 0.f, v1 = 0.f, v2 = 0.f, v3 = 0.f,
          v4 = 0.f, v5 = 0.f, v6 = 0.f, v7 = 0.f;
    if (active) {
        const float4 s4 = *reinterpret_cast<const float4*>(Smean + (size_t)row * T_DIM + t0);
        const float4 a4 = *reinterpret_cast<const float4*>(Amean + (size_t)row * T_DIM + t0);
        const float sarr[4] = {s4.x, s4.y, s4.z, s4.w};
        const float aarr[4] = {a4.x, a4.y, a4.z, a4.w};
#pragma unroll
        for (int j = 0; j < 4; ++j) {
            const int t = t0 + j;
            const float s  = sarr[j];
            const float a  = aarr[j];
            const float sa = s * a;
            if (t < slen) {
                const bool sup = a < theta;
                if (pos) {
                    const float ls  = fmaxf(__logf(s),  -100.0f);
                    const float lsa = fmaxf(__logf(sa), -100.0f);
                    v0 += ls;
                    v1 += lsa;
                    v2 += sup ? ls  : -100.0f;   // log(0) clamped
                    v3 += sup ? lsa : -100.0f;
                    v4 += fabsf(a);
                    if (isLG) v5 += (a - s) * (a - s);
                } else {
                    const float ls  = fmaxf(__logf(1.0f - s),  -100.0f);
                    const float lsa = fmaxf(__logf(1.0f - sa), -100.0f);
                    v0 += ls;
                    v1 += lsa;
                    if (sup) { v2 += ls; v3 += lsa; }  // !sup -> log(1)=0
                    if (isLG) v5 += a * a;
                }
                v7 += s + sa;
            }
            if (t < slen - 1) {
                float s2, a2;
                if (j < 3) { s2 = sarr[j + 1]; a2 = aarr[j + 1]; }
                else {
                    s2 = Smean[(size_t)row * T_DIM + t + 1];
                    a2 = Amean[(size_t)row * T_DIM + t + 1];
                }
                const float ds  = s  - s2;
                const float dsa = sa - s2 * a2;
                v6 += ds * ds + dsa * dsa;
            }
        }
    }

    float vals[8] = {v0, v1, v2, v3, v4, v5, v6, v7};
#pragma unroll
    for (int k = 0; k < 8; ++k)
#pragma unroll
        for (int off = 32; off; off >>= 1)
            vals[k] += __shfl_down(vals[k], off, 64);

    __shared__ float red[BWAVE][8];
    if (lane == 0)
#pragma unroll
        for (int k = 0; k < 8; ++k) red[w][k] = vals[k];
    __syncthreads();

    if (tid == 0) {
        float t8[8];
#pragma unroll
        for (int k = 0; k < 8; ++k) t8[k] = red[0][k];
        for (int w2 = 1; w2 < BWAVE; ++w2)
#pragma unroll
            for (int k = 0; k < 8; ++k) t8[k] += red[w2][k];

        const float inv_slen = 1.0f / (float)slen;
        const float invB2    = 2.0f / (float)B;   // 1/128

        atomicAdd(out + 0, ALPHA_C          * (-t8[0] * inv_slen) * invB2);
        atomicAdd(out + 1, ALPHA_C          * (-t8[1] * inv_slen) * invB2);
        atomicAdd(out + 2, (1.0f - ALPHA_C) * (-t8[2] * inv_slen) * invB2);
        atomicAdd(out + 3, (1.0f - ALPHA_C) * (-t8[3] * inv_slen) * invB2);
        if (pos)               atomicAdd(out + 4, GAMMA_C * t8[4] * invB2);
        if (row == B - 1)        atomicAdd(out + 5, t8[5] * inv_slen);  // LG_0
        if (row == (B >> 1) - 1) atomicAdd(out + 6, t8[5] * inv_slen);  // LG_1
        atomicAdd(out + 7, MU_C * t8[6] * invB2);
        atomicAdd(out + 8, t8[7] * invB2);
    }
}

extern "C" void kernel_launch(void* const* d_in, const int* in_sizes, int n_in,
                              void* d_out, int out_size, void* d_ws, size_t ws_size,
                              hipStream_t stream) {
    const float* scores = (const float*)d_in[0];
    const float* attw   = (const float*)d_in[1];
    // d_in[2] = label (unused: reference splits by fixed B/2)
    const int*   seqlen = (const int*)d_in[3];
    const int B = in_sizes[2];

    hipMemsetAsync(d_out, 0, out_size * sizeof(float), stream);
    mbs_means<<<dim3(B * NCH), dim3(ATHR), 0, stream>>>(scores, attw, seqlen,
                                                        (float*)d_ws, B);
    mbs_final<<<dim3(B), dim3(BTHR), 0, stream>>>(seqlen, (const float*)d_ws,
                                                  (float*)d_out, B);
}

// Round 6
// 19.821 us; speedup vs baseline: 3.7467x; 2.3834x over previous
//
#include <hip/hip_runtime.h>
#include <math.h>

// Problem constants (match reference)
constexpr int   T_DIM = 4096;
constexpr int   NC    = 10;
constexpr int   NTHR  = 1024;          // 16 waves/block, one block per batch row
constexpr int   NWAVE = NTHR / 64;
constexpr int   PSTRIDE = 16;          // floats per partial-row in d_ws

constexpr float EPS_C   = 0.2f;
constexpr float ALPHA_C = 0.5f;
constexpr float GAMMA_C = 1e-4f;
constexpr float MU_C    = 8e-4f;

__global__ __launch_bounds__(NTHR) void mbs_pass1(
    const float* __restrict__ scores,
    const float* __restrict__ attw,
    const int*   __restrict__ seqlen,
    float*       __restrict__ part,    // [B][PSTRIDE] per-block contributions
    int B)
{
    __shared__ float s_lds[T_DIM];
    __shared__ float a_lds[T_DIM];
    __shared__ float red_mx[NWAVE];
    __shared__ float red_mn[NWAVE];
    __shared__ float red_sum[NWAVE][8];
    __shared__ float sh_theta;

    const int tid  = threadIdx.x;
    const int lane = tid & 63;
    const int wid  = tid >> 6;
    const int b    = blockIdx.x;
    const int slen = seqlen[b];
    const bool pos = b < (B >> 1);
    const int t0   = tid * 4;
    const bool active = t0 < slen;     // elements t>=slen are never used by ANY term

    // ---------- pass 1: channel mean, HIGH-MLP load body ----------
    // Two batches of 10 independent float4 loads into NAMED registers so the
    // compiler cannot serialize them into a 2-deep load->waitcnt->add chain
    // (R2's 52-VGPR kernel did exactly that => ~2.2 TB/s cap).
    float4 s4 = make_float4(0.f, 0.f, 0.f, 0.f);
    float4 a4 = make_float4(0.f, 0.f, 0.f, 0.f);
    if (active) {
        const float* sp = scores + (size_t)b * NC * T_DIM + t0;
        const float* ap = attw   + (size_t)b * NC * T_DIM + t0;
#pragma unroll
        for (int h = 0; h < 2; ++h) {
            float4 sv[5], av[5];
#pragma unroll
            for (int c = 0; c < 5; ++c)
                sv[c] = *reinterpret_cast<const float4*>(sp + (size_t)(h * 5 + c) * T_DIM);
#pragma unroll
            for (int c = 0; c < 5; ++c)
                av[c] = *reinterpret_cast<const float4*>(ap + (size_t)(h * 5 + c) * T_DIM);
#pragma unroll
            for (int c = 0; c < 5; ++c) {
                s4.x += sv[c].x; s4.y += sv[c].y; s4.z += sv[c].z; s4.w += sv[c].w;
                a4.x += av[c].x; a4.y += av[c].y; a4.z += av[c].z; a4.w += av[c].w;
            }
        }
        const float invNC = 1.0f / (float)NC;
        s4.x *= invNC; s4.y *= invNC; s4.z *= invNC; s4.w *= invNC;
        a4.x *= invNC; a4.y *= invNC; a4.z *= invNC; a4.w *= invNC;

        reinterpret_cast<float4*>(s_lds)[tid] = s4;
        reinterpret_cast<float4*>(a_lds)[tid] = a4;
    }

    const float sarr[4] = {s4.x, s4.y, s4.z, s4.w};
    const float aarr[4] = {a4.x, a4.y, a4.z, a4.w};

    float amax = -INFINITY, amin = INFINITY;
    if (active) {
#pragma unroll
        for (int j = 0; j < 4; ++j) {
            if (t0 + j < slen) {
                amax = fmaxf(amax, aarr[j]);
                amin = fminf(amin, aarr[j]);
            }
        }
    }
#pragma unroll
    for (int off = 32; off; off >>= 1) {
        amax = fmaxf(amax, __shfl_down(amax, off, 64));
        amin = fminf(amin, __shfl_down(amin, off, 64));
    }
    if (lane == 0) { red_mx[wid] = amax; red_mn[wid] = amin; }
    __syncthreads();   // also publishes s_lds/a_lds for pass-2 neighbor reads
    if (tid == 0) {
        float mx = red_mx[0], mn = red_mn[0];
#pragma unroll
        for (int w = 1; w < NWAVE; ++w) {
            mx = fmaxf(mx, red_mx[w]);
            mn = fminf(mn, red_mn[w]);
        }
        sh_theta = (mx - mn) * EPS_C + mn;
    }
    __syncthreads();
    const float theta = sh_theta;

    // ---------- pass 2: all reductions from registers (+LDS neighbor) ----------
    // v0=log(S) bce, v1=log(SA) bce, v2=sup bce(S), v3=sup bce(SA),
    // v4=sum|A| (pos rows), v5=LG sum (rows B/2-1, B-1), v6=smooth, v7=spread
    float v0 = 0.f, v1 = 0.f, v2 = 0.f, v3 = 0.f,
          v4 = 0.f, v5 = 0.f, v6 = 0.f, v7 = 0.f;
    const bool isLG = (b == (B >> 1) - 1) || (b == B - 1);

    if (active) {
#pragma unroll
        for (int j = 0; j < 4; ++j) {
            const int t   = t0 + j;
            const float s  = sarr[j];
            const float a  = aarr[j];
            const float sa = s * a;
            if (t < slen) {
                const bool sup = a < theta;
                if (pos) {
                    const float ls  = fmaxf(__logf(s),  -100.0f);
                    const float lsa = fmaxf(__logf(sa), -100.0f);
                    v0 += ls;
                    v1 += lsa;
                    v2 += sup ? ls  : -100.0f;   // log(0) clamped
                    v3 += sup ? lsa : -100.0f;
                    v4 += fabsf(a);
                    if (isLG) v5 += (a - s) * (a - s);
                } else {
                    const float ls  = fmaxf(__logf(1.0f - s),  -100.0f);
                    const float lsa = fmaxf(__logf(1.0f - sa), -100.0f);
                    v0 += ls;
                    v1 += lsa;
                    if (sup) { v2 += ls; v3 += lsa; }  // !sup -> log(1-0)=0
                    if (isLG) v5 += a * a;
                }
                v7 += s + sa;
            }
            if (t < slen - 1) {   // t+1 < slen, owner thread of t+1 was active
                const float s2 = (j < 3) ? sarr[j + 1] : s_lds[t + 1];
                const float a2 = (j < 3) ? aarr[j + 1] : a_lds[t + 1];
                const float ds  = s  - s2;
                const float dsa = sa - s2 * a2;
                v6 += ds * ds + dsa * dsa;
            }
        }
    }

    // ---------- block reduce 8 sums ----------
    float vals[8] = {v0, v1, v2, v3, v4, v5, v6, v7};
#pragma unroll
    for (int k = 0; k < 8; ++k) {
#pragma unroll
        for (int off = 32; off; off >>= 1)
            vals[k] += __shfl_down(vals[k], off, 64);
    }
    if (lane == 0) {
#pragma unroll
        for (int k = 0; k < 8; ++k) red_sum[wid][k] = vals[k];
    }
    __syncthreads();

    if (tid == 0) {
        float tot[8];
#pragma unroll
        for (int k = 0; k < 8; ++k) tot[k] = 0.f;
        for (int w = 0; w < NWAVE; ++w)
#pragma unroll
            for (int k = 0; k < 8; ++k) tot[k] += red_sum[w][k];

        const float inv_slen = 1.0f / (float)slen;
        const float invB2    = 2.0f / (float)B;   // 1/128

        float* p = part + (size_t)b * PSTRIDE;
        p[0] = ALPHA_C          * (-tot[0] * inv_slen) * invB2;
        p[1] = ALPHA_C          * (-tot[1] * inv_slen) * invB2;
        p[2] = (1.0f - ALPHA_C) * (-tot[2] * inv_slen) * invB2;
        p[3] = (1.0f - ALPHA_C) * (-tot[3] * inv_slen) * invB2;
        p[4] = pos ? (GAMMA_C * tot[4] * invB2) : 0.0f;
        p[5] = (b == B - 1)        ? tot[5] * inv_slen : 0.0f;  // LG_0 (row B-1)
        p[6] = (b == (B >> 1) - 1) ? tot[5] * inv_slen : 0.0f;  // LG_1 (row B/2-1)
        p[7] = MU_C * tot[6] * invB2;
        p[8] = tot[7] * invB2;
    }
}

__global__ __launch_bounds__(64) void mbs_pass2(
    const float* __restrict__ part,
    float*       __restrict__ out,
    int B)
{
    float acc[9];
#pragma unroll
    for (int k = 0; k < 9; ++k) acc[k] = 0.f;
    for (int r = (int)threadIdx.x; r < B; r += 64) {
        const float* p = part + (size_t)r * PSTRIDE;
#pragma unroll
        for (int k = 0; k < 9; ++k) acc[k] += p[k];
    }
#pragma unroll
    for (int k = 0; k < 9; ++k) {
#pragma unroll
        for (int off = 32; off; off >>= 1)
            acc[k] += __shfl_down(acc[k], off, 64);
    }
    if (threadIdx.x == 0) {
#pragma unroll
        for (int k = 0; k < 9; ++k) out[k] = acc[k];
    }
}

extern "C" void kernel_launch(void* const* d_in, const int* in_sizes, int n_in,
                              void* d_out, int out_size, void* d_ws, size_t ws_size,
                              hipStream_t stream) {
    const float* scores = (const float*)d_in[0];
    const float* attw   = (const float*)d_in[1];
    // d_in[2] = label (unused: reference splits by fixed B/2)
    const int*   seqlen = (const int*)d_in[3];
    const int B = in_sizes[2];

    float* part = (float*)d_ws;   // B * PSTRIDE floats, rewritten every launch

    mbs_pass1<<<dim3(B), dim3(NTHR), 0, stream>>>(scores, attw, seqlen, part, B);
    mbs_pass2<<<dim3(1), dim3(64), 0, stream>>>(part, (float*)d_out, B);
}